// Round 18
// baseline (3225.541 us; speedup 1.0000x reference)
//
#include <hip/hip_runtime.h>

#define B_N 16
#define T_N 15
#define CIN 64
#define COUT 128
#define HS 56
#define HWN 3136
#define XSP 3364              // 58*58 padded plane
#define NSG (16 * 128 * 28 * 28)

// PROVEN reference model (R10, absmax=0.0):
//   conv: per-output flat sequential FMA chain, k-order (kh, kw, ci-innermost),
//         bias separate rounded add. fma(+/-0,w,acc)==acc bit-exact.
//   elementwise/scan: per-op rounding, no FMA.
// R16/R17 lessons: LDS-x + SMEM-w share lgkmcnt (oOo SMEM -> full drains);
// global-x thrashes L1. This round: x wave-uniform from padded NHWC scratch
// (scalar/broadcast loads, 16KB/tap working set), w per-lane coalesced global
// (lane=co), no LDS in hot loop. Chain order per output unchanged (px is a
// parallel dim; tap-major ci-ascending preserved).

// ---------- weight transpose: w[co][ci][kh][kw] -> wt4[tap][ci][co]
__global__ void wt_kernel(const float* __restrict__ w, float* __restrict__ wt4) {
    int i = blockIdx.x * 256 + threadIdx.x;  // 0 .. 73727
    if (i >= COUT * 576) return;
    int co = i / 576;
    int r = i - co * 576;      // ci*9 + kh*3 + kw
    int ci = r / 9;
    int kk = r - ci * 9;       // kh*3+kw
    wt4[((size_t)kk * CIN + ci) * COUT + co] = w[i];
}

// ---------- zero-fill x_s ----------
__global__ void zero_xs(float4* __restrict__ p, long n4) {
    long i = (long)blockIdx.x * 256 + threadIdx.x;
    long stride = (long)gridDim.x * 256;
    for (; i < n4; i += stride) p[i] = make_float4(0.f, 0.f, 0.f, 0.f);
}

// ---------- transpose x NCHW -> padded NHWC x_s[btc][(h+1)*58+(w+1)][ci] ----
__global__ __launch_bounds__(256) void tr_kernel(
    const float* __restrict__ x, float* __restrict__ xs, int t0)
{
    __shared__ float t[64][65];
    const int blk = blockIdx.x;
    const int hwt = blk % 49;            // 49 tiles of 64 hw
    const int btc = blk / 49;            // tc*16+b
    const int b = btc & 15;
    const int tt = t0 + (btc >> 4);
    const int hw0 = hwt * 64;
    const int tid = threadIdx.x;

    const float* xb = x + ((size_t)(b * T_N + tt) * CIN) * HWN;
#pragma unroll
    for (int k = 0; k < 16; ++k) {
        int ci = (tid >> 6) * 16 + k;
        int hwl = tid & 63;
        t[ci][hwl] = xb[(size_t)ci * HWN + hw0 + hwl];
    }
    __syncthreads();
#pragma unroll
    for (int k = 0; k < 16; ++k) {
        int hwl = (tid >> 6) * 16 + k;
        int ci = tid & 63;
        int hw = hw0 + hwl;
        int ph = hw / 56, pw = hw - ph * 56;
        xs[((size_t)btc * XSP + (ph + 1) * 58 + (pw + 1)) * CIN + ci] = t[ci][hwl];
    }
}

// ---------- conv: wave = (tile, rowhalf, cohalf); lane = co; x uniform ----
__global__ __launch_bounds__(256) void conv_smem(
    const float* __restrict__ xs, const float* __restrict__ wt4,
    const float* __restrict__ bias, float* __restrict__ obuf, int nz)
{
    __shared__ float tb[4][16 * 68];     // per-wave transpose buffers

    const int bid = blockIdx.x;
    const int zb = (bid & 7) * (nz >> 3) + (bid >> 3);  // XCD swizzle

    const int lane = threadIdx.x & 63;
    const int wslot = threadIdx.x >> 6;
    const int wid = __builtin_amdgcn_readfirstlane(zb * 4 + wslot);

    const int ch = wid & 1;              // co half
    const int rh = (wid >> 1) & 1;       // row half
    const int rest = wid >> 2;
    const int tile = rest % 49;
    const int btc = rest / 49;           // tc*16+b

    const int h0 = (tile / 7) * 8 + rh * 4;
    const int w0c = (tile % 7) * 8;
    const int co = ch * 64 + lane;

    const float* xsb = xs + (size_t)btc * XSP * CIN;

    float acc[32];
#pragma unroll
    for (int i = 0; i < 32; ++i) acc[i] = 0.0f;

    for (int kh = 0; kh < 3; ++kh) {
        for (int kw = 0; kw < 3; ++kw) {
            // wave-uniform x base for this tap (padded: no bounds checks)
            const float* xtap = xsb + ((size_t)((h0 + kh) * 58 + (w0c + kw))) * CIN;
            const float* wtap = wt4 + ((size_t)(kh * 3 + kw) * CIN) * COUT + co;
            for (int c8 = 0; c8 < 16; ++c8) {
                // per-lane coalesced weight loads (VMEM, L1/L2-hot)
                const float wv0 = wtap[(c8 * 4 + 0) * COUT];
                const float wv1 = wtap[(c8 * 4 + 1) * COUT];
                const float wv2 = wtap[(c8 * 4 + 2) * COUT];
                const float wv3 = wtap[(c8 * 4 + 3) * COUT];
                const float* xc = xtap + c8 * 4;
#pragma unroll
                for (int i = 0; i < 32; ++i) {
                    // wave-uniform 16B read; same line across lanes
                    const float4 xq = *(const float4*)(xc + ((i >> 3) * 58 + (i & 7)) * CIN);
                    acc[i] = fmaf(xq.x, wv0, acc[i]);
                    acc[i] = fmaf(xq.y, wv1, acc[i]);
                    acc[i] = fmaf(xq.z, wv2, acc[i]);
                    acc[i] = fmaf(xq.w, wv3, acc[i]);
                }
            }
        }
    }

    // bias (separate rounded add)
    const float bv = bias[co];
#pragma unroll
    for (int i = 0; i < 32; ++i) acc[i] = __fadd_rn(acc[i], bv);

    // wave-local LDS transpose -> NCHW store (rec32 layout unchanged)
    float* T = &tb[wslot][0];
    const size_t obase = (size_t)(btc * COUT) * HWN;
#pragma unroll
    for (int c = 0; c < 2; ++c) {
#pragma unroll
        for (int i = 0; i < 16; ++i) T[i * 68 + lane] = acc[c * 16 + i];
        // wave-synchronous: compiler inserts lgkm waits for T reuse
#pragma unroll
        for (int r = 0; r < 16; ++r) {
            const int col = (lane >> 4) + r * 4;           // co_local
            const int pxl = (lane & 15);                   // px within chunk
            const float v = T[pxl * 68 + col];
            const int px = c * 16 + pxl;
            const int hh = h0 + (px >> 3);
            const int ww = w0c + (px & 7);
            obuf[obase + (size_t)(ch * 64 + col) * HWN + hh * HS + ww] = v;
        }
    }
}

// ---------- recurrence, strict fp32, in-kernel t-loop (UNCHANGED) ----------
__global__ __launch_bounds__(256) void rec32(
    const float* __restrict__ cvbuf, const float* __restrict__ fcw,
    const float* __restrict__ fcb, float* __restrict__ stateD,
    unsigned* __restrict__ stateS, float* __restrict__ out,
    int t0, int nt, int doLoad, int doStore)
{
    const int idx = blockIdx.x * 256 + threadIdx.x;  // 16*128*784 sites
    const int pw = idx % 28;
    int tmp = idx / 28;
    const int ph = tmp % 28;
    tmp /= 28;
    const int co = tmp & 127;
    const int b = tmp >> 7;

    const size_t g = (size_t)idx;

    const float w0 = fcw[0], w1 = fcw[1], w2 = fcw[2], fb = fcb[0];

    float u[4], m3[4], s[4];
    if (doLoad) {
        unsigned sm = stateS[g];
#pragma unroll
        for (int p = 0; p < 4; ++p) {
            u[p] = stateD[(size_t)p * NSG + g];
            m3[p] = stateD[(size_t)(4 + p) * NSG + g];
            s[p] = (float)((sm >> p) & 1u);
        }
    } else {
#pragma unroll
        for (int p = 0; p < 4; ++p) { u[p] = 0.0f; m3[p] = 0.0f; s[p] = 0.0f; }
    }

    const int h0 = ph * 2, wc0 = pw * 2;

    for (int tc = 0; tc < nt; ++tc) {
        const size_t cbase = ((size_t)(tc * 16 + b) * COUT + co) * HWN
                           + (size_t)h0 * HS + wc0;
        const float cv[4] = {cvbuf[cbase], cvbuf[cbase + 1],
                             cvbuf[cbase + HS], cvbuf[cbase + HS + 1]};

#pragma unroll
        for (int p = 0; p < 4; ++p) {
            float e0 = __fadd_rn(__fadd_rn(__fmul_rn(u[p], w0), __fmul_rn(u[p], w1)),
                                 __fmul_rn(u[p], w2));
            float x4 = __fadd_rn(e0, fb);
            float dd = __fmul_rn(0.2f, __fsub_rn(1.0f, s[p]));
            u[p]  = __fadd_rn(__fmul_rn(u[p], dd), cv[p]);
            m3[p] = __fadd_rn(__fmul_rn(m3[p], dd), x4);
            float e1 = __fadd_rn(__fadd_rn(__fmul_rn(u[p], w0), __fmul_rn(u[p], w1)),
                                 __fmul_rn(u[p], w2));
            float mem1 = __fadd_rn(__fadd_rn(e1, fb), m3[p]);
            s[p] = (__fsub_rn(mem1, 0.8f) > 0.0f) ? 1.0f : 0.0f;
        }

        float pooled = 0.25f * (((s[0] + s[1]) + s[2]) + s[3]);
        out[(((size_t)b * T_N + (t0 + tc)) * COUT + co) * 784 + ph * 28 + pw] = pooled;
    }

    if (doStore) {
        unsigned sm = 0;
#pragma unroll
        for (int p = 0; p < 4; ++p) {
            stateD[(size_t)p * NSG + g] = u[p];
            stateD[(size_t)(4 + p) * NSG + g] = m3[p];
            sm |= (s[p] > 0.5f) ? (1u << p) : 0u;
        }
        stateS[g] = sm;
    }
}

extern "C" void kernel_launch(void* const* d_in, const int* in_sizes, int n_in,
                              void* d_out, int out_size, void* d_ws, size_t ws_size,
                              hipStream_t stream) {
    const float* x     = (const float*)d_in[0];
    const float* cw    = (const float*)d_in[1];
    const float* cbias = (const float*)d_in[2];
    const float* fcw   = (const float*)d_in[3];
    const float* fcb   = (const float*)d_in[4];
    float* out = (float*)d_out;

    const size_t wtB   = (size_t)576 * COUT * sizeof(float);            // 294 KB
    const size_t convT = (size_t)B_N * COUT * HWN * sizeof(float);      // 25.69 MB/t
    const size_t xsT   = (size_t)B_N * XSP * CIN * sizeof(float);       // 13.78 MB/t
    const size_t statB = (size_t)NSG * 8 * sizeof(float)
                       + (size_t)NSG * sizeof(unsigned);                // ~57.8 MB

    int Tc;
    if (wtB + (size_t)T_N * (convT + xsT) <= ws_size) {
        Tc = T_N;
    } else if (ws_size > wtB + statB + convT + xsT) {
        Tc = (int)((ws_size - wtB - statB) / (convT + xsT));
        if (Tc > T_N) Tc = T_N;
    } else {
        return;  // ws unusably small
    }

    float* wt4 = (float*)d_ws;
    float* convbuf = (float*)((char*)d_ws + wtB);
    float* xsbuf = (float*)((char*)d_ws + wtB + (size_t)Tc * convT);
    float* stateD = (float*)((char*)d_ws + wtB + (size_t)Tc * (convT + xsT));
    unsigned* stateS = (unsigned*)((char*)stateD + (size_t)NSG * 8 * sizeof(float));

    wt_kernel<<<(COUT * 576 + 255) / 256, 256, 0, stream>>>(cw, wt4);

    for (int t0 = 0; t0 < T_N; t0 += Tc) {
        const int nt = (T_N - t0 < Tc) ? (T_N - t0) : Tc;
        const int nbt = nt * 16;
        const long n4 = (long)nbt * XSP * CIN / 4;
        zero_xs<<<2048, 256, 0, stream>>>((float4*)xsbuf, n4);
        tr_kernel<<<nbt * 49, 256, 0, stream>>>(x, xsbuf, t0);
        const int nz = nbt * 49;                 // blocks (4 waves each)
        conv_smem<<<nz, 256, 0, stream>>>(xsbuf, wt4, cbias, convbuf, nz);
        rec32<<<NSG / 256, 256, 0, stream>>>(
            convbuf, fcw, fcb, stateD, stateS, out,
            t0, nt, t0 > 0 ? 1 : 0, (t0 + nt) < T_N ? 1 : 0);
    }
}

// Round 19
// 1441.443 us; speedup vs baseline: 2.2377x; 2.2377x over previous
//
#include <hip/hip_runtime.h>

#define B_N 16
#define T_N 15
#define CIN 64
#define COUT 128
#define HS 56
#define HWN 3136
#define NSG (16 * 128 * 28 * 28)

// PROVEN reference model (R10/R14, absmax=0.0):
//   conv: per-output flat sequential FMA chain, k-order (kh, kw, ci-innermost),
//         bias as separate rounded add. fma(+/-0,w,acc)==acc bit-exact.
//   elementwise/scan: per-op rounding, no FMA.
// Perf history: R16 (LDS-x + SGPR-w, 32co/lane-px) = best, VALUBusy 65%.
// R17/R18 (x via global) regressed: FETCH 4-6x, L1 can't hold x tiles.
// This round: R16 + batched ds_reads (xv[8]) -> lgkmcnt(0) drain exposes
// LDS latency once per 256 FMAs instead of once per 32. Chain order
// unchanged (batching = inner-loop tiling; ci still 0..63 asc per tap).

// ---------- weight transpose: w[co][ci][kh][kw] -> wt4[tap][ci][co]
__global__ void wt_kernel(const float* __restrict__ w, float* __restrict__ wt4) {
    int i = blockIdx.x * 256 + threadIdx.x;  // 0 .. 73727
    if (i >= COUT * 576) return;
    int co = i / 576;
    int r = i - co * 576;      // ci*9 + kh*3 + kw
    int ci = r / 9;
    int kk = r - ci * 9;       // kh*3+kw
    wt4[((size_t)kk * CIN + ci) * COUT + co] = w[i];
}

// ---------- conv: 4 waves x (64 px lanes x 32 co acc), weights in SGPR ----
__global__ __launch_bounds__(256) void conv_sgpr(
    const float* __restrict__ x, const float* __restrict__ wt4,
    const float* __restrict__ bias, float* __restrict__ obuf,
    int t0, int nz)
{
    __shared__ float xs[CIN * 100];   // [ci][10][10], zero halo

    // XCD-chunked swizzle (nz divisible by 8)
    const int bid = blockIdx.x;
    const int z = (bid & 7) * (nz >> 3) + (bid >> 3);

    const int tile = z % 49;
    const int u = z / 49;
    const int b = u & 15;
    const int tc = u >> 4;

    const int ty = tile / 7, tx = tile - ty * 7;
    const int h0 = ty * 8, w0c = tx * 8;

    const int tid = threadIdx.x;

    // ---- stage x tile [64][10][10], +0.0f padding ----
    const float* xb = x + ((size_t)(b * T_N + (t0 + tc)) * CIN) * HWN;
    for (int i = tid; i < CIN * 100; i += 256) {
        int ci = i / 100;
        int rem = i - ci * 100;
        int rr = rem / 10;
        int cc = rem - rr * 10;
        int gh = h0 - 1 + rr;
        int gw = w0c - 1 + cc;
        float v = 0.0f;
        if ((unsigned)gh < (unsigned)HS && (unsigned)gw < (unsigned)HS)
            v = xb[(size_t)ci * HWN + gh * HS + gw];
        xs[i] = v;
    }
    __syncthreads();

    const int lane = tid & 63;
    const int wv = __builtin_amdgcn_readfirstlane(tid >> 6);  // 0..3, uniform
    const int co0 = wv * 32;
    const int lh = lane >> 3;       // local row 0..7
    const int lw = lane & 7;        // local col 0..7

    float acc[32];
#pragma unroll
    for (int j = 0; j < 32; ++j) acc[j] = 0.0f;

    for (int kh = 0; kh < 3; ++kh) {
        for (int kw = 0; kw < 3; ++kw) {
            const int xoff = (lh + kh) * 10 + (lw + kw);
            // uniform weight base for this (tap, wave)
            const float* wk = wt4 + ((size_t)(kh * 3 + kw) * CIN) * COUT + co0;
            for (int c8 = 0; c8 < 8; ++c8) {
                // batch 8 LDS reads -> one latency exposure per 256 FMAs
                float xv[8];
#pragma unroll
                for (int k = 0; k < 8; ++k)
                    xv[k] = xs[(c8 * 8 + k) * 100 + xoff];
#pragma unroll
                for (int k = 0; k < 8; ++k) {
                    const int ci = c8 * 8 + k;
#pragma unroll
                    for (int j = 0; j < 32; ++j) {
                        // wk[..] wave-uniform -> s_load; FMA: SGPRxVGPR+VGPR
                        acc[j] = fmaf(xv[k], wk[ci * COUT + j], acc[j]);
                    }
                }
            }
        }
    }

    // bias (separate rounded add) + store: lanes = consecutive px -> coalesced
    const int h = h0 + lh;
    const int wq = w0c + lw;
    const size_t obase = ((size_t)(tc * 16 + b) * COUT + co0) * HWN
                       + (size_t)h * HS + wq;
#pragma unroll
    for (int j = 0; j < 32; ++j) {
        obuf[obase + (size_t)j * HWN] = __fadd_rn(acc[j], bias[co0 + j]);
    }
}

// ---------- recurrence, strict fp32, in-kernel t-loop ----------
__global__ __launch_bounds__(256) void rec32(
    const float* __restrict__ cvbuf, const float* __restrict__ fcw,
    const float* __restrict__ fcb, float* __restrict__ stateD,
    unsigned* __restrict__ stateS, float* __restrict__ out,
    int t0, int nt, int doLoad, int doStore)
{
    const int idx = blockIdx.x * 256 + threadIdx.x;  // 16*128*784 sites
    const int pw = idx % 28;
    int tmp = idx / 28;
    const int ph = tmp % 28;
    tmp /= 28;
    const int co = tmp & 127;
    const int b = tmp >> 7;

    const size_t g = (size_t)idx;

    const float w0 = fcw[0], w1 = fcw[1], w2 = fcw[2], fb = fcb[0];

    float u[4], m3[4], s[4];
    if (doLoad) {
        unsigned sm = stateS[g];
#pragma unroll
        for (int p = 0; p < 4; ++p) {
            u[p] = stateD[(size_t)p * NSG + g];
            m3[p] = stateD[(size_t)(4 + p) * NSG + g];
            s[p] = (float)((sm >> p) & 1u);
        }
    } else {
#pragma unroll
        for (int p = 0; p < 4; ++p) { u[p] = 0.0f; m3[p] = 0.0f; s[p] = 0.0f; }
    }

    const int h0 = ph * 2, wc0 = pw * 2;

    for (int tc = 0; tc < nt; ++tc) {
        const size_t cbase = ((size_t)(tc * 16 + b) * COUT + co) * HWN
                           + (size_t)h0 * HS + wc0;
        const float cv[4] = {cvbuf[cbase], cvbuf[cbase + 1],
                             cvbuf[cbase + HS], cvbuf[cbase + HS + 1]};

#pragma unroll
        for (int p = 0; p < 4; ++p) {
            float e0 = __fadd_rn(__fadd_rn(__fmul_rn(u[p], w0), __fmul_rn(u[p], w1)),
                                 __fmul_rn(u[p], w2));
            float x4 = __fadd_rn(e0, fb);
            float dd = __fmul_rn(0.2f, __fsub_rn(1.0f, s[p]));
            u[p]  = __fadd_rn(__fmul_rn(u[p], dd), cv[p]);
            m3[p] = __fadd_rn(__fmul_rn(m3[p], dd), x4);
            float e1 = __fadd_rn(__fadd_rn(__fmul_rn(u[p], w0), __fmul_rn(u[p], w1)),
                                 __fmul_rn(u[p], w2));
            float mem1 = __fadd_rn(__fadd_rn(e1, fb), m3[p]);
            s[p] = (__fsub_rn(mem1, 0.8f) > 0.0f) ? 1.0f : 0.0f;
        }

        float pooled = 0.25f * (((s[0] + s[1]) + s[2]) + s[3]);
        out[(((size_t)b * T_N + (t0 + tc)) * COUT + co) * 784 + ph * 28 + pw] = pooled;
    }

    if (doStore) {
        unsigned sm = 0;
#pragma unroll
        for (int p = 0; p < 4; ++p) {
            stateD[(size_t)p * NSG + g] = u[p];
            stateD[(size_t)(4 + p) * NSG + g] = m3[p];
            sm |= (s[p] > 0.5f) ? (1u << p) : 0u;
        }
        stateS[g] = sm;
    }
}

extern "C" void kernel_launch(void* const* d_in, const int* in_sizes, int n_in,
                              void* d_out, int out_size, void* d_ws, size_t ws_size,
                              hipStream_t stream) {
    const float* x     = (const float*)d_in[0];
    const float* cw    = (const float*)d_in[1];
    const float* cbias = (const float*)d_in[2];
    const float* fcw   = (const float*)d_in[3];
    const float* fcb   = (const float*)d_in[4];
    float* out = (float*)d_out;

    const size_t wtB   = (size_t)576 * COUT * sizeof(float);        // 294 KB
    const size_t convT = (size_t)B_N * COUT * HWN * sizeof(float);  // 25.69 MB / t
    const size_t statB = (size_t)NSG * 8 * sizeof(float)
                       + (size_t)NSG * sizeof(unsigned);            // ~57.8 MB

    int Tc;
    if (wtB + (size_t)T_N * convT <= ws_size) {
        Tc = T_N;                                   // no state spill needed
    } else if (ws_size > wtB + statB + convT) {
        Tc = (int)((ws_size - wtB - statB) / convT);
        if (Tc > T_N) Tc = T_N;
    } else {
        return;  // ws unusably small
    }

    float* wt4 = (float*)d_ws;
    float* convbuf = (float*)((char*)d_ws + wtB);
    float* stateD = (float*)((char*)d_ws + wtB + (size_t)Tc * convT);
    unsigned* stateS = (unsigned*)((char*)stateD + (size_t)NSG * 8 * sizeof(float));

    wt_kernel<<<(COUT * 576 + 255) / 256, 256, 0, stream>>>(cw, wt4);

    for (int t0 = 0; t0 < T_N; t0 += Tc) {
        const int nt = (T_N - t0 < Tc) ? (T_N - t0) : Tc;
        const int nz = nt * 16 * 49;                // divisible by 8
        conv_sgpr<<<nz, 256, 0, stream>>>(x, wt4, cbias, convbuf, t0, nz);
        rec32<<<NSG / 256, 256, 0, stream>>>(
            convbuf, fcw, fcb, stateD, stateS, out,
            t0, nt, t0 > 0 ? 1 : 0, (t0 + nt) < T_N ? 1 : 0);
    }
}